// Round 4
// baseline (22.053 us; speedup 1.0000x reference)
//
#include <hip/hip_runtime.h>

// MedianFilter2D: 3x3 median, reflect pad, [16,3,512,512] f32.
// Per-row horizontal sorted triple (hmin,hmed,hmax) over cols j-1..j+1;
// median9 = med3( max3(hmin x3 rows), med3(hmed x3 rows), min3(hmax x3 rows) ).
// Each thread: 4-column group x R=16 consecutive output rows, rolling triples.
// Halo columns come from neighboring lanes via __shfl (not memory): the two
// per-row scalar edge loads cost the TA/L1 as much as the main dwordx4 while
// delivering 1/4 the bytes; shuffles ride the idle LDS pipe instead.

constexpr int Wd = 512;
constexpr int Hd = 512;
constexpr int R  = 16;  // output rows per thread

__device__ __forceinline__ float med3f(float a, float b, float c) {
    return __builtin_amdgcn_fmed3f(a, b, c);
}
__device__ __forceinline__ float min3f(float a, float b, float c) {
    return fminf(fminf(a, b), c);   // v_min3_f32
}
__device__ __forceinline__ float max3f(float a, float b, float c) {
    return fmaxf(fmaxf(a, b), c);   // v_max3_f32
}

struct Trip { float mn[4], md[4], mx[4]; };

__global__ __launch_bounds__(256) void MedianFilter2D_68745246540291_kernel(
    const float* __restrict__ in, float* __restrict__ out, int total) {
    int idx = blockIdx.x * blockDim.x + threadIdx.x;
    if (idx >= total) return;

    int lane = threadIdx.x & 63;
    int cg   = idx & 127;          // column group (4 cols each)
    int w4   = cg << 2;
    int rt   = (idx >> 7) & 31;    // row tile within plane (H/R = 32)
    int r0   = rt * R;
    long plane = (long)(idx >> 12);

    const float* p = in  + plane * (long)(Hd * Wd);
    float*       q = out + plane * (long)(Hd * Wd);

    auto loadrow = [&](int g) -> Trip {
        int h = (g < 0) ? 1 : ((g > Hd - 1) ? Hd - 2 : g);   // reflect rows
        const float* rp = p + (long)h * Wd;
        float4 c4 = *reinterpret_cast<const float4*>(rp + w4);
        // halo columns from neighbor lanes (wave covers 64 consecutive cgs)
        float v0 = __shfl_up(c4.w, 1);
        float v5 = __shfl_down(c4.x, 1);
        if (lane == 0)  v0 = (cg == 0)   ? c4.y : rp[w4 - 1];  // reflect or 1-lane load
        if (lane == 63) v5 = (cg == 127) ? c4.z : rp[w4 + 4];
        float v[6] = { v0, c4.x, c4.y, c4.z, c4.w, v5 };
        Trip t;
#pragma unroll
        for (int j = 0; j < 4; ++j) {
            t.mn[j] = min3f(v[j], v[j + 1], v[j + 2]);
            t.md[j] = med3f(v[j], v[j + 1], v[j + 2]);
            t.mx[j] = max3f(v[j], v[j + 1], v[j + 2]);
        }
        return t;
    };

    Trip t0 = loadrow(r0 - 1);
    Trip t1 = loadrow(r0);
#pragma unroll
    for (int i = 0; i < R; ++i) {
        Trip t2 = loadrow(r0 + i + 1);
        float4 o;
        float* op = &o.x;
#pragma unroll
        for (int j = 0; j < 4; ++j) {
            float lo = max3f(t0.mn[j], t1.mn[j], t2.mn[j]);
            float mi = med3f(t0.md[j], t1.md[j], t2.md[j]);
            float hi = min3f(t0.mx[j], t1.mx[j], t2.mx[j]);
            op[j] = med3f(lo, mi, hi);
        }
        *reinterpret_cast<float4*>(q + (long)(r0 + i) * Wd + w4) = o;
        t0 = t1;
        t1 = t2;
    }
}

extern "C" void kernel_launch(void* const* d_in, const int* in_sizes, int n_in,
                              void* d_out, int out_size, void* d_ws, size_t ws_size,
                              hipStream_t stream) {
    const float* in = (const float*)d_in[0];
    float* out = (float*)d_out;
    int total = out_size / (4 * R);            // threads: 4 cols x R rows each
    int block = 256;
    int grid = (total + block - 1) / block;    // 768 blocks
    MedianFilter2D_68745246540291_kernel<<<grid, block, 0, stream>>>(in, out, total);
}

// Round 6
// 21.718 us; speedup vs baseline: 1.0154x; 1.0154x over previous
//
#include <hip/hip_runtime.h>

// MedianFilter2D: 3x3 median, reflect pad, [16,3,512,512] f32.
// Per-row horizontal sorted triple (hmin,hmed,hmax); median9 =
// med3( max3(hmin x3), med3(hmed x3), min3(hmax x3) ).
// Each thread: 4-col group x R=16 rows, rolling triples.
// R5: fix R4 compile error — use clang ext_vector float4 for
// __builtin_nontemporal_store (HIP_vector_type not accepted).

constexpr int Wd = 512;
constexpr int Hd = 512;
constexpr int R  = 16;  // output rows per thread

typedef float f32x4 __attribute__((ext_vector_type(4)));

__device__ __forceinline__ float med3f(float a, float b, float c) {
    return __builtin_amdgcn_fmed3f(a, b, c);
}
__device__ __forceinline__ float min3f(float a, float b, float c) {
    return fminf(fminf(a, b), c);   // v_min3_f32
}
__device__ __forceinline__ float max3f(float a, float b, float c) {
    return fmaxf(fmaxf(a, b), c);   // v_max3_f32
}

struct Trip { float mn[4], md[4], mx[4]; };

__global__ __launch_bounds__(256) void MedianFilter2D_68745246540291_kernel(
    const float* __restrict__ in, float* __restrict__ out, int total) {
    int idx = blockIdx.x * blockDim.x + threadIdx.x;
    if (idx >= total) return;

    int lane = threadIdx.x & 63;
    int cg   = idx & 127;          // column group (4 cols each)
    int w4   = cg << 2;
    int rt   = (idx >> 7) & 31;    // row tile within plane (H/R = 32)
    int r0   = rt * R;
    long plane = (long)(idx >> 12);

    const float* p = in  + plane * (long)(Hd * Wd);
    float*       q = out + plane * (long)(Hd * Wd);

    auto rowptr = [&](int g) -> const float* {
        int h = (g < 0) ? 1 : ((g > Hd - 1) ? Hd - 2 : g);   // reflect rows
        return p + (long)h * Wd;
    };
    auto loadraw = [&](int g) -> f32x4 {
        return *reinterpret_cast<const f32x4*>(rowptr(g) + w4);
    };
    // build triple from a raw float4 (halo cols via cross-lane shuffle)
    auto mktrip = [&](f32x4 c4, int g) -> Trip {
        float v0 = __shfl_up(c4.w, 1);
        float v5 = __shfl_down(c4.x, 1);
        if (lane == 0)  v0 = (cg == 0)   ? c4.y : rowptr(g)[w4 - 1];
        if (lane == 63) v5 = (cg == 127) ? c4.z : rowptr(g)[w4 + 4];
        float v[6] = { v0, c4.x, c4.y, c4.z, c4.w, v5 };
        Trip t;
#pragma unroll
        for (int j = 0; j < 4; ++j) {
            t.mn[j] = min3f(v[j], v[j + 1], v[j + 2]);
            t.md[j] = med3f(v[j], v[j + 1], v[j + 2]);
            t.mx[j] = max3f(v[j], v[j + 1], v[j + 2]);
        }
        return t;
    };

    // prologue: rows r0-1, r0 consumed into triples; row r0+1 raw in flight
    f32x4 rawC = loadraw(r0 - 1);
    f32x4 rawD = loadraw(r0);
    Trip t0 = mktrip(rawC, r0 - 1);
    rawC = loadraw(r0 + 1);
    Trip t1 = mktrip(rawD, r0);

#pragma unroll
    for (int i = 0; i < R; ++i) {
        // issue load for row i+2 before consuming row i+1 (depth-2 pipeline)
        if (i < R - 1) rawD = loadraw(r0 + i + 2);
        Trip t2 = mktrip(rawC, r0 + i + 1);
        f32x4 o;
#pragma unroll
        for (int j = 0; j < 4; ++j) {
            float lo = max3f(t0.mn[j], t1.mn[j], t2.mn[j]);
            float mi = med3f(t0.md[j], t1.md[j], t2.md[j]);
            float hi = min3f(t0.mx[j], t1.mx[j], t2.mx[j]);
            o[j] = med3f(lo, mi, hi);
        }
        __builtin_nontemporal_store(o, reinterpret_cast<f32x4*>(
            q + (long)(r0 + i) * Wd + w4));
        t0 = t1;
        t1 = t2;
        rawC = rawD;
    }
}

extern "C" void kernel_launch(void* const* d_in, const int* in_sizes, int n_in,
                              void* d_out, int out_size, void* d_ws, size_t ws_size,
                              hipStream_t stream) {
    const float* in = (const float*)d_in[0];
    float* out = (float*)d_out;
    int total = out_size / (4 * R);            // threads: 4 cols x R rows each
    int block = 256;
    int grid = (total + block - 1) / block;    // 768 blocks
    MedianFilter2D_68745246540291_kernel<<<grid, block, 0, stream>>>(in, out, total);
}